// Round 7
// baseline (4100.889 us; speedup 1.0000x reference)
//
#include <hip/hip_runtime.h>

typedef unsigned short USH;
typedef __attribute__((ext_vector_type(8))) short bf16x8;
typedef __attribute__((ext_vector_type(4))) float f32x4;
typedef __attribute__((ext_vector_type(4))) USH u16x4;

// HIDDEN=512 VOCAB=32000 SRC=50 TGT-steps=49 BATCH=64
// M_dec = 49*64 = 3136 (padded to 3200), total steps = 99, Aemb rows = 6336

__device__ __forceinline__ USH f2bf(float x) {
  unsigned u = __float_as_uint(x);
  u += 0x7fffu + ((u >> 16) & 1u);   // round-to-nearest-even
  return (USH)(u >> 16);
}
__device__ __forceinline__ float bf2f(USH u) { return __uint_as_float(((unsigned)u) << 16); }
__device__ __forceinline__ float sigm(float x) { return 1.f / (1.f + __expf(-x)); }
__device__ __forceinline__ float tanh_(float x) {
  x = fminf(fmaxf(x, -15.f), 15.f);
  float e = __expf(2.f * x);
  return (e - 1.f) / (e + 1.f);
}

// ---------------------------------------------------------------- prep (everything the recurrence needs; W_out conversion lives in recur's converter blocks)
__global__ void prep_kernel(const int* __restrict__ in_lines, const int* __restrict__ tg_lines,
                            const float* __restrict__ emb_in, const float* __restrict__ emb_tgt,
                            const float* __restrict__ WihE, const float* __restrict__ WhhE,
                            const float* __restrict__ bihE, const float* __restrict__ bhhE,
                            const float* __restrict__ WihD, const float* __restrict__ WhhD,
                            const float* __restrict__ bihD, const float* __restrict__ bhhD,
                            USH* __restrict__ WihEbf, USH* __restrict__ WhhEbf,
                            USH* __restrict__ WihDbf, USH* __restrict__ WhhDbf,
                            USH* __restrict__ Aemb, USH* __restrict__ hbuf, USH* __restrict__ Hdec,
                            float* __restrict__ bsumE, float* __restrict__ bsumD,
                            float* __restrict__ S, float* __restrict__ loss_tl,
                            int* __restrict__ flags) {
  const size_t tid = (size_t)blockIdx.x * blockDim.x + threadIdx.x;
  const size_t stride = (size_t)gridDim.x * blockDim.x;

  // 4 LSTM weight mats -> bf16 : 2048*512/4 each
  {
    const float* wsrc[4] = {WihE, WhhE, WihD, WhhD};
    USH* wdst[4] = {WihEbf, WhhEbf, WihDbf, WhhDbf};
#pragma unroll
    for (int w = 0; w < 4; ++w) {
      const float4* s4 = (const float4*)wsrc[w];
      USH* d = wdst[w];
      for (size_t i = tid; i < 262144u; i += stride) {
        float4 v = s4[i];
        u16x4 o = {f2bf(v.x), f2bf(v.y), f2bf(v.z), f2bf(v.w)};
        *(u16x4*)(d + i * 4) = o;
      }
    }
  }
  // embedding gather -> Aemb bf16 : 6336 rows x 512 (/4)
  for (size_t i = tid; i < 811008u; i += stride) {
    int m = (int)(i >> 7), k4 = (int)(i & 127);
    int tok; const float* etab;
    if (m < 3200) { tok = in_lines[m]; etab = emb_in; }         // enc rows: step*64+b
    else          { tok = tg_lines[m - 3200]; etab = emb_tgt; } // dec rows: tgt_in flat
    float4 v = *(const float4*)(etab + (size_t)tok * 512 + k4 * 4);
    u16x4 o = {f2bf(v.x), f2bf(v.y), f2bf(v.z), f2bf(v.w)};
    *(u16x4*)(Aemb + i * 4) = o;
  }
  // combined biases
  for (size_t i = tid; i < 2048u; i += stride) {
    bsumE[i] = bihE[i] + bhhE[i];
    bsumD[i] = bihD[i] + bhhD[i];
  }
  // zeros: h0 (buffer 0, 64KB), Hdec pad rows 3136..3199, S, loss, flags
  uint4 z = make_uint4(0, 0, 0, 0);
  for (size_t i = tid; i < 4096u; i += stride) ((uint4*)hbuf)[i] = z;
  for (size_t i = tid; i < 4096u; i += stride) ((uint4*)(Hdec + (size_t)3136 * 512))[i] = z;
  for (size_t i = tid; i < 800u; i += stride) ((uint4*)S)[i] = z;
  if (tid < 256) flags[tid] = 0;     // 4 groups x 64 ints (32 used per group)
  if (tid == 0) loss_tl[0] = 0.f;
}

// ---------------------------------------------------------------- recurrence + W_out converter
// PLAIN launch (capture-safe): 256 blocks x 256 threads <= 256 CUs -> co-residency
// by capacity, so the custom flag barrier cannot deadlock.
// XCD-clustered decode (MI355X round-robins blocks across 8 XCDs by bid%8):
//   xcd = bid&7, slot = bid>>3.
//   xcd<4  -> LSTM block (bb=xcd, jb=slot): group bb's 32 blocks all land on XCD bb
//             -> h-tile + flag traffic stays on one XCD's L2/coherence path.
//   xcd>=4 -> W_out fp32->bf16 converter (128 blocks on XCDs 4..7): streams 96MB
//             at HBM rate without evicting the LSTM XCDs' L2 working set.
// If the bid%8 mapping assumption is wrong this is just a permutation: correctness
// and co-residency are unaffected, only locality changes.
// LSTM block (jb,bb): hidden cols [jb*16..+16) x batch rows [bb*16..+16). Wave g
// computes gate g's 16x16 tile (K=1024); W_ih/W_hh fragments live in VGPRs (128
// regs). The 4 bb-groups are independent sequential chains -> group-local barriers
// (32 blocks, flags packed per group). Dual accumulator chains halve exposed MFMA
// latency. Next-step x-part MFMA overlaps the flag poll.
__global__ __launch_bounds__(256, 1) void recur_kernel(
    const USH* __restrict__ Aemb,
    const USH* __restrict__ WihEbf, const USH* __restrict__ WhhEbf,
    const USH* __restrict__ WihDbf, const USH* __restrict__ WhhDbf,
    const float* __restrict__ bsumE, const float* __restrict__ bsumD,
    USH* __restrict__ hbuf, USH* __restrict__ Hdec, int* __restrict__ flags,
    const float* __restrict__ Wout, USH* __restrict__ WoutBf) {
  __shared__ float gex[4][16][17];   // [gate][b_local][j_local], padded stride 17
  const int bid = blockIdx.x;
  const int tid = threadIdx.x;
  const int xcd = bid & 7, slot = bid >> 3;

  if (xcd >= 4) {   // ---- converter blocks: W_out -> bf16, then exit ----
    const float4* s4 = (const float4*)Wout;
    const int cid = (xcd - 4) * 32 + slot;           // 0..127
    size_t i = (size_t)cid * 256 + tid;
#pragma unroll 5
    for (int it = 0; it < 125; ++it, i += 32768) {   // 125*32768 = 4,096,000
      float4 v = s4[i];
      u16x4 o = {f2bf(v.x), f2bf(v.y), f2bf(v.z), f2bf(v.w)};
      *(u16x4*)(WoutBf + i * 4) = o;
    }
    return;
  }

  const int jb = slot, bb = xcd;
  const int j0 = jb * 16;
  const int wid = tid >> 6, lane = tid & 63;
  const int l15 = lane & 15, lhi = lane >> 4;
  const int klo = lhi * 8;                 // this lane's 8-elem chunk within a K=32 slice
  const int bl = tid >> 4, jl = tid & 15;  // elementwise cell (b_local, j_local)
  const size_t wrow = (size_t)(wid * 512 + j0 + l15) * 512;  // this lane's W row base
  int* gflags = flags + bb * 64;           // this group's 32 flags, packed

  // W fragments in registers: 16 K-slices each for W_ih and W_hh (gate wid, cols j0..j0+15)
  bf16x8 wf[16], hf[16];
#pragma unroll
  for (int kc = 0; kc < 16; ++kc) {
    wf[kc] = *(const bf16x8*)(WihEbf + wrow + kc * 32 + klo);
    hf[kc] = *(const bf16x8*)(WhhEbf + wrow + kc * 32 + klo);
  }

  f32x4 acc0, acc1;   // dual independent chains (even/odd K-slices)
  auto xpart = [&](int s) {   // acc = bias + x(s) @ W_ih^T  (gate wid; independent of h)
    const float* bs = (s >= 50) ? bsumD : bsumE;
    float b = bs[wid * 512 + j0 + l15];
    f32x4 tb = {b, b, b, b};
    f32x4 tz = {0.f, 0.f, 0.f, 0.f};
    acc0 = tb; acc1 = tz;
    const USH* ax = Aemb + ((size_t)s * 64 + bb * 16 + l15) * 512 + klo;
#pragma unroll
    for (int kc = 0; kc < 16; kc += 2) {
      acc0 = __builtin_amdgcn_mfma_f32_16x16x32_bf16(*(const bf16x8*)(ax + kc * 32), wf[kc], acc0, 0, 0, 0);
      acc1 = __builtin_amdgcn_mfma_f32_16x16x32_bf16(*(const bf16x8*)(ax + (kc + 1) * 32), wf[kc + 1], acc1, 0, 0, 0);
    }
  };

  float cst = 0.f;
  xpart(0);

  for (int step = 0; step < 99; ++step) {
    // h-part: acc += h(step) @ W_hh^T  (A rows shared by all 4 waves -> L1; B resident)
    const USH* ah = hbuf + (size_t)(step & 1) * 32768 + (size_t)(bb * 16 + l15) * 512 + klo;
#pragma unroll
    for (int kc = 0; kc < 16; kc += 2) {
      acc0 = __builtin_amdgcn_mfma_f32_16x16x32_bf16(*(const bf16x8*)(ah + kc * 32), hf[kc], acc0, 0, 0, 0);
      acc1 = __builtin_amdgcn_mfma_f32_16x16x32_bf16(*(const bf16x8*)(ah + (kc + 1) * 32), hf[kc + 1], acc1, 0, 0, 0);
    }

    // gate exchange: wave g publishes its 16x16 tile (C-layout row=lhi*4+r, col=l15)
#pragma unroll
    for (int r = 0; r < 4; ++r) gex[wid][lhi * 4 + r][l15] = acc0[r] + acc1[r];
    __syncthreads();

    // elementwise LSTM: one cell per thread
    const bool dec = (step >= 50);
    {
      float gi = gex[0][bl][jl], gf = gex[1][bl][jl], gg = gex[2][bl][jl], go = gex[3][bl][jl];
      float cn = sigm(gf) * cst + sigm(gi) * tanh_(gg);
      cst = cn;
      float hn = sigm(go) * tanh_(cn);
      USH hb = f2bf(hn);
      const int brow = bb * 16 + bl;
      hbuf[(size_t)((step + 1) & 1) * 32768 + (size_t)brow * 512 + j0 + jl] = hb;
      if (dec) Hdec[((size_t)(step - 50) * 64 + brow) * 512 + j0 + jl] = hb;
    }

    if (step == 49) {   // enc->dec: swap register-resident weights (before xpart(50))
#pragma unroll
      for (int kc = 0; kc < 16; ++kc) {
        wf[kc] = *(const bf16x8*)(WihDbf + wrow + kc * 32 + klo);
        hf[kc] = *(const bf16x8*)(WhhDbf + wrow + kc * 32 + klo);
      }
    }

    if (step < 98) {
      // -------- arrive (group-local) --------
      __threadfence();              // h stores -> agent-visible
      __syncthreads();              // all lanes fenced; gex reads done (safe to rewrite)
      if (tid == 0)
        __hip_atomic_store(&gflags[jb], step + 1, __ATOMIC_RELEASE, __HIP_MEMORY_SCOPE_AGENT);
      // -------- overlap: next step's x-part (Aemb + register W only) --------
      xpart(step + 1);
      // -------- wait: poll own group's 32 packed flags, one per lane --------
      if (wid == 0 && lane < 32) {
        int v;
        do { v = __hip_atomic_load(&gflags[lane], __ATOMIC_RELAXED, __HIP_MEMORY_SCOPE_AGENT); } while (v <= step);
      }
      __threadfence();              // acquire: invalidate before reading fresh h
      __syncthreads();
    }
  }
}

// ---------------------------------------------------------------- projection (m97-style 128x128, XCD-swizzled)
__global__ __launch_bounds__(256) void proj_kernel(const USH* __restrict__ Hdec,
                                                   const USH* __restrict__ WoutBf,
                                                   const float* __restrict__ bout,
                                                   float* __restrict__ S) {
  __shared__ USH Alds[128 * 64];
  __shared__ USH Blds[128 * 64];
  __shared__ float rowsum[128];
  // bijective XCD swizzle (m204): nwg=6250 = 8*781+2 -> residues 0,1 get 782 blocks
  const int xcd = blockIdx.x & 7, idx = blockIdx.x >> 3;
  const int wg = (xcd < 2 ? xcd * 782 : 2 * 782 + (xcd - 2) * 781) + idx;
  const int mt = wg % 25, nt = wg / 25;   // 25 consecutive wg share one W_out slab
  const int m0 = mt * 128, n0 = nt * 128;
  const int tid = threadIdx.x;
  const int wid = tid >> 6, lane = tid & 63;
  const int l15 = lane & 15, lhi = lane >> 4;
  const int wr = wid >> 1, wc = wid & 1;
  if (tid < 128) rowsum[tid] = 0.f;

  f32x4 acc[4][4];
  {
    f32x4 z = {0.f, 0.f, 0.f, 0.f};
#pragma unroll
    for (int mi = 0; mi < 4; ++mi)
#pragma unroll
      for (int ni = 0; ni < 4; ++ni) acc[mi][ni] = z;
  }
  const int lrow8 = lane >> 3, lcolb = (lane & 7) * 16;

  for (int kt = 0; kt < 8; ++kt) {
#pragma unroll
    for (int i = 0; i < 4; ++i) {
      int q = wid * 4 + i;                 // 0..15, each covers 8 tile rows
      int row = q * 8 + lrow8;
      const char* ga = (const char*)Hdec   + ((size_t)(m0 + row) * 512 + kt * 64) * 2 + lcolb;
      const char* gb = (const char*)WoutBf + ((size_t)(n0 + row) * 512 + kt * 64) * 2 + lcolb;
      __builtin_amdgcn_global_load_lds((const __attribute__((address_space(1))) void*)ga,
                                       (__attribute__((address_space(3))) void*)&Alds[q * 512], 16, 0, 0);
      __builtin_amdgcn_global_load_lds((const __attribute__((address_space(1))) void*)gb,
                                       (__attribute__((address_space(3))) void*)&Blds[q * 512], 16, 0, 0);
    }
    __syncthreads();
#pragma unroll
    for (int kk = 0; kk < 2; ++kk) {
      bf16x8 a[4], b[4];
#pragma unroll
      for (int mi = 0; mi < 4; ++mi)
        a[mi] = *(const bf16x8*)&Alds[(wr * 64 + mi * 16 + l15) * 64 + kk * 32 + lhi * 8];
#pragma unroll
      for (int ni = 0; ni < 4; ++ni)
        b[ni] = *(const bf16x8*)&Blds[(wc * 64 + ni * 16 + l15) * 64 + kk * 32 + lhi * 8];
#pragma unroll
      for (int mi = 0; mi < 4; ++mi)
#pragma unroll
        for (int ni = 0; ni < 4; ++ni)
          acc[mi][ni] = __builtin_amdgcn_mfma_f32_16x16x32_bf16(a[mi], b[ni], acc[mi][ni], 0, 0, 0);
    }
    __syncthreads();
  }
  // epilogue: bias + exp + per-row sum -> S (logits never hit memory)
  float bias[4];
#pragma unroll
  for (int ni = 0; ni < 4; ++ni) bias[ni] = bout[n0 + wc * 64 + ni * 16 + l15];
#pragma unroll
  for (int mi = 0; mi < 4; ++mi) {
#pragma unroll
    for (int r = 0; r < 4; ++r) {
      float s = 0.f;
#pragma unroll
      for (int ni = 0; ni < 4; ++ni) s += __expf(acc[mi][ni][r] + bias[ni]);
      s += __shfl_xor(s, 1);
      s += __shfl_xor(s, 2);
      s += __shfl_xor(s, 4);
      s += __shfl_xor(s, 8);
      if (l15 == 0) atomicAdd(&rowsum[wr * 64 + mi * 16 + lhi * 4 + r], s);
    }
  }
  __syncthreads();
  if (tid < 128) atomicAdd(&S[m0 + tid], rowsum[tid]);
}

// ---------------------------------------------------------------- target logits
__global__ void tgt_kernel(const USH* __restrict__ Hdec, const USH* __restrict__ WoutBf,
                           const float* __restrict__ bout, const int* __restrict__ tg_lines,
                           float* __restrict__ loss_tl) {
  __shared__ float part[4];
  const int tid = threadIdx.x;
  const int wid = tid >> 6, lane = tid & 63;
  const int g = blockIdx.x * 4 + wid;        // 0..3135
  const int t = g >> 6, b = g & 63;
  const int v = tg_lines[(t + 1) * 64 + b];  // tgt_next
  bf16x8 hv = *(const bf16x8*)(Hdec + (size_t)g * 512 + lane * 8);
  bf16x8 wv = *(const bf16x8*)(WoutBf + (size_t)v * 512 + lane * 8);
  float s = 0.f;
#pragma unroll
  for (int j = 0; j < 8; ++j) s += bf2f((USH)hv[j]) * bf2f((USH)wv[j]);
#pragma unroll
  for (int m = 1; m < 64; m <<= 1) s += __shfl_xor(s, m);
  if (lane == 0) part[wid] = s + bout[v];
  __syncthreads();
  if (tid == 0) atomicAdd(loss_tl, part[0] + part[1] + part[2] + part[3]);
}

// ---------------------------------------------------------------- finalize
__global__ void fin_kernel(const float* __restrict__ S, const float* __restrict__ loss_tl,
                           float* __restrict__ out) {
  __shared__ float part[4];
  const int tid = threadIdx.x;
  float s = 0.f;
  for (int m = tid; m < 3136; m += 256) s += logf(S[m]);
#pragma unroll
  for (int m = 1; m < 64; m <<= 1) s += __shfl_xor(s, m);
  if ((tid & 63) == 0) part[tid >> 6] = s;
  __syncthreads();
  if (tid == 0) out[0] = (part[0] + part[1] + part[2] + part[3] - loss_tl[0]) * (1.f / 64.f);
}

// ---------------------------------------------------------------- launch
extern "C" void kernel_launch(void* const* d_in, const int* in_sizes, int n_in,
                              void* d_out, int out_size, void* d_ws, size_t ws_size,
                              hipStream_t stream) {
  (void)in_sizes; (void)n_in; (void)out_size; (void)ws_size;
  const int* in_lines  = (const int*)d_in[0];
  const int* tg_lines  = (const int*)d_in[1];
  const float* emb_in  = (const float*)d_in[2];
  const float* emb_tgt = (const float*)d_in[3];
  const float* WihE = (const float*)d_in[4];
  const float* WhhE = (const float*)d_in[5];
  const float* bihE = (const float*)d_in[6];
  const float* bhhE = (const float*)d_in[7];
  const float* WihD = (const float*)d_in[8];
  const float* WhhD = (const float*)d_in[9];
  const float* bihD = (const float*)d_in[10];
  const float* bhhD = (const float*)d_in[11];
  const float* Wout = (const float*)d_in[12];
  const float* bout = (const float*)d_in[13];

  char* ws = (char*)d_ws;
  USH* WoutBf  = (USH*)(ws + 0u);          // 32,768,000
  USH* WihEbf  = (USH*)(ws + 32768000u);   // +2,097,152 each
  USH* WhhEbf  = (USH*)(ws + 34865152u);
  USH* WihDbf  = (USH*)(ws + 36962304u);
  USH* WhhDbf  = (USH*)(ws + 39059456u);
  USH* Aemb    = (USH*)(ws + 41156608u);   // 6336*512*2 = 6,488,064
  USH* hbuf    = (USH*)(ws + 47644672u);   // 2 * 64*512*2 = 131,072
  USH* Hdec    = (USH*)(ws + 47775744u);   // 3200*512*2 = 3,276,800
  float* S     = (float*)(ws + 51052544u); // 3200*4
  float* bsumE = (float*)(ws + 51065344u);
  float* bsumD = (float*)(ws + 51073536u);
  float* loss_tl = (float*)(ws + 51081728u);
  int* flags   = (int*)(ws + 51085312u);   // 4 groups x 64 ints (packed per group)

  prep_kernel<<<1024, 256, 0, stream>>>(in_lines, tg_lines, emb_in, emb_tgt,
      WihE, WhhE, bihE, bhhE, WihD, WhhD, bihD, bhhD,
      WihEbf, WhhEbf, WihDbf, WhhDbf, Aemb, hbuf, Hdec, bsumE, bsumD, S, loss_tl, flags);

  // plain launch (capture-safe); 256 blocks <= 256 CUs -> co-resident by capacity.
  // bid&7 < 4 -> LSTM (group bb=bid&7 clustered on one XCD); bid&7 >= 4 -> W_out converter
  recur_kernel<<<256, 256, 0, stream>>>(Aemb, WihEbf, WhhEbf, WihDbf, WhhDbf,
                                        bsumE, bsumD, hbuf, Hdec, flags, Wout, WoutBf);

  proj_kernel<<<6250, 256, 0, stream>>>(Hdec, WoutBf, bout, S);
  tgt_kernel<<<784, 256, 0, stream>>>(Hdec, WoutBf, bout, tg_lines, loss_tl);
  fin_kernel<<<1, 256, 0, stream>>>(S, loss_tl, (float*)d_out);
}

// Round 11
// 1138.417 us; speedup vs baseline: 3.6023x; 3.6023x over previous
//
#include <hip/hip_runtime.h>

typedef unsigned short USH;
typedef unsigned long long ULL;
typedef __attribute__((ext_vector_type(8))) short bf16x8;
typedef __attribute__((ext_vector_type(4))) float f32x4;
typedef __attribute__((ext_vector_type(4))) USH u16x4;

// HIDDEN=512 VOCAB=32000 SRC=50 TGT-steps=49 BATCH=64
// M_dec = 49*64 = 3136 (padded to 3200), total steps = 99, Aemb rows = 6336

__device__ __forceinline__ USH f2bf(float x) {
  unsigned u = __float_as_uint(x);
  u += 0x7fffu + ((u >> 16) & 1u);   // round-to-nearest-even
  return (USH)(u >> 16);
}
__device__ __forceinline__ float bf2f(USH u) { return __uint_as_float(((unsigned)u) << 16); }
__device__ __forceinline__ float sigm(float x) { return 1.f / (1.f + __expf(-x)); }
__device__ __forceinline__ float tanh_(float x) {
  x = fminf(fmaxf(x, -15.f), 15.f);
  float e = __expf(2.f * x);
  return (e - 1.f) / (e + 1.f);
}

// agent-scope coherent 16B load as 2x8B relaxed atomics (bypass stale
// L1/per-XCD-L2, read the device coherence point; NO cache-maintenance ops)
__device__ __forceinline__ bf16x8 ld_h16(const USH* p) {
  ULL* q = const_cast<ULL*>((const ULL*)p);
  ULL a = __hip_atomic_load(q,     __ATOMIC_RELAXED, __HIP_MEMORY_SCOPE_AGENT);
  ULL b = __hip_atomic_load(q + 1, __ATOMIC_RELAXED, __HIP_MEMORY_SCOPE_AGENT);
  union { ULL u[2]; bf16x8 v; } c;
  c.u[0] = a; c.u[1] = b;
  return c.v;
}

// ---------------------------------------------------------------- prep
__global__ void prep_kernel(const int* __restrict__ in_lines, const int* __restrict__ tg_lines,
                            const float* __restrict__ emb_in, const float* __restrict__ emb_tgt,
                            const float* __restrict__ WihE, const float* __restrict__ WhhE,
                            const float* __restrict__ bihE, const float* __restrict__ bhhE,
                            const float* __restrict__ WihD, const float* __restrict__ WhhD,
                            const float* __restrict__ bihD, const float* __restrict__ bhhD,
                            USH* __restrict__ WihEbf, USH* __restrict__ WhhEbf,
                            USH* __restrict__ WihDbf, USH* __restrict__ WhhDbf,
                            USH* __restrict__ Aemb, USH* __restrict__ hbuf, USH* __restrict__ Hdec,
                            float* __restrict__ bsumE, float* __restrict__ bsumD,
                            float* __restrict__ S, float* __restrict__ loss_tl,
                            int* __restrict__ flags) {
  const size_t tid = (size_t)blockIdx.x * blockDim.x + threadIdx.x;
  const size_t stride = (size_t)gridDim.x * blockDim.x;

  // 4 LSTM weight mats -> bf16 : 2048*512/4 each
  {
    const float* wsrc[4] = {WihE, WhhE, WihD, WhhD};
    USH* wdst[4] = {WihEbf, WhhEbf, WihDbf, WhhDbf};
#pragma unroll
    for (int w = 0; w < 4; ++w) {
      const float4* s4 = (const float4*)wsrc[w];
      USH* d = wdst[w];
      for (size_t i = tid; i < 262144u; i += stride) {
        float4 v = s4[i];
        u16x4 o = {f2bf(v.x), f2bf(v.y), f2bf(v.z), f2bf(v.w)};
        *(u16x4*)(d + i * 4) = o;
      }
    }
  }
  // embedding gather -> Aemb bf16 : 6336 rows x 512 (/4)
  for (size_t i = tid; i < 811008u; i += stride) {
    int m = (int)(i >> 7), k4 = (int)(i & 127);
    int tok; const float* etab;
    if (m < 3200) { tok = in_lines[m]; etab = emb_in; }         // enc rows: step*64+b
    else          { tok = tg_lines[m - 3200]; etab = emb_tgt; } // dec rows: tgt_in flat
    float4 v = *(const float4*)(etab + (size_t)tok * 512 + k4 * 4);
    u16x4 o = {f2bf(v.x), f2bf(v.y), f2bf(v.z), f2bf(v.w)};
    *(u16x4*)(Aemb + i * 4) = o;
  }
  // combined biases
  for (size_t i = tid; i < 2048u; i += stride) {
    bsumE[i] = bihE[i] + bhhE[i];
    bsumD[i] = bihD[i] + bhhD[i];
  }
  // zeros: h0 (buffer 0, 64KB), Hdec pad rows 3136..3199, S, loss, flags
  uint4 z = make_uint4(0, 0, 0, 0);
  for (size_t i = tid; i < 4096u; i += stride) ((uint4*)hbuf)[i] = z;
  for (size_t i = tid; i < 4096u; i += stride) ((uint4*)(Hdec + (size_t)3136 * 512))[i] = z;
  for (size_t i = tid; i < 800u; i += stride) ((uint4*)S)[i] = z;
  if (tid < 256) flags[tid] = 0;     // 4 groups x 64 ints (32 used per group)
  if (tid == 0) loss_tl[0] = 0.f;
}

// ---------------------------------------------------------------- recurrence + W_out converter
// FENCE-FREE inter-block protocol (r7 counters: __threadfence()'s
// buffer_wbl2/buffer_inv whole-L2 ops cost ~37us/step -> MfmaUtil 0.28%):
//   - h stores:  relaxed agent-scope 32-bit atomics (write-through to the
//     device coherence point; pair of bf16 packed via shfl so the atomic is
//     word-sized -> guaranteed native global_store_dword lowering)
//   - h loads:   relaxed agent-scope 8B atomic loads (bypass stale L1/L2)
//   - arrive:    __syncthreads() drains vmcnt (agent stores then visible
//     device-wide) -> tid0 posts RELAXED flag; h-visible-before-flag holds
//     without a release fence because the h stores themselves wrote through.
//   - wait:      relaxed poll + sched_barrier(0) (compiler order pin; hardware
//     order via in-order issue + control dep + s_barrier).
// XCD-clustered decode: xcd=bid&7; xcd<4 -> LSTM block (bb=xcd, jb=bid>>3):
// group bb's 32 blocks land on one XCD. xcd>=4 -> W_out fp32->bf16 converter.
// LSTM block (jb,bb): hidden cols [jb*16..+16) x batch rows [bb*16..+16).
// Wave g computes gate g's 16x16 tile (K=1024); W fragments live in VGPRs.
// Dual accumulator chains halve exposed MFMA latency; next-step x-part MFMA
// overlaps the flag poll.
__global__ __launch_bounds__(256, 1) void recur_kernel(
    const USH* __restrict__ Aemb,
    const USH* __restrict__ WihEbf, const USH* __restrict__ WhhEbf,
    const USH* __restrict__ WihDbf, const USH* __restrict__ WhhDbf,
    const float* __restrict__ bsumE, const float* __restrict__ bsumD,
    USH* __restrict__ hbuf, USH* __restrict__ Hdec, int* __restrict__ flags,
    const float* __restrict__ Wout, USH* __restrict__ WoutBf) {
  __shared__ float gex[4][16][17];   // [gate][b_local][j_local], padded stride 17
  const int bid = blockIdx.x;
  const int tid = threadIdx.x;
  const int xcd = bid & 7, slot = bid >> 3;

  if (xcd >= 4) {   // ---- converter blocks: W_out -> bf16, then exit ----
    const float4* s4 = (const float4*)Wout;
    const int cid = (xcd - 4) * 32 + slot;           // 0..127
    size_t i = (size_t)cid * 256 + tid;
#pragma unroll 5
    for (int it = 0; it < 125; ++it, i += 32768) {   // 125*32768 = 4,096,000
      float4 v = s4[i];
      u16x4 o = {f2bf(v.x), f2bf(v.y), f2bf(v.z), f2bf(v.w)};
      *(u16x4*)(WoutBf + i * 4) = o;
    }
    return;
  }

  const int jb = slot, bb = xcd;
  const int j0 = jb * 16;
  const int wid = tid >> 6, lane = tid & 63;
  const int l15 = lane & 15, lhi = lane >> 4;
  const int klo = lhi * 8;                 // this lane's 8-elem chunk within a K=32 slice
  const int bl = tid >> 4, jl = tid & 15;  // elementwise cell (b_local, j_local)
  const size_t wrow = (size_t)(wid * 512 + j0 + l15) * 512;  // this lane's W row base
  int* gflags = flags + bb * 64;           // this group's 32 flags, packed

  // W fragments in registers: 16 K-slices each for W_ih and W_hh (gate wid, cols j0..j0+15)
  bf16x8 wf[16], hf[16];
#pragma unroll
  for (int kc = 0; kc < 16; ++kc) {
    wf[kc] = *(const bf16x8*)(WihEbf + wrow + kc * 32 + klo);
    hf[kc] = *(const bf16x8*)(WhhEbf + wrow + kc * 32 + klo);
  }

  f32x4 acc0, acc1;   // dual independent chains (even/odd K-slices)
  auto xpart = [&](int s) {   // acc = bias + x(s) @ W_ih^T  (gate wid; independent of h)
    const float* bs = (s >= 50) ? bsumD : bsumE;
    float b = bs[wid * 512 + j0 + l15];
    f32x4 tb = {b, b, b, b};
    f32x4 tz = {0.f, 0.f, 0.f, 0.f};
    acc0 = tb; acc1 = tz;
    const USH* ax = Aemb + ((size_t)s * 64 + bb * 16 + l15) * 512 + klo;
#pragma unroll
    for (int kc = 0; kc < 16; kc += 2) {
      acc0 = __builtin_amdgcn_mfma_f32_16x16x32_bf16(*(const bf16x8*)(ax + kc * 32), wf[kc], acc0, 0, 0, 0);
      acc1 = __builtin_amdgcn_mfma_f32_16x16x32_bf16(*(const bf16x8*)(ax + (kc + 1) * 32), wf[kc + 1], acc1, 0, 0, 0);
    }
  };

  float cst = 0.f;
  xpart(0);

  for (int step = 0; step < 99; ++step) {
    // h-part: acc += h(step) @ W_hh^T  (A rows via agent-coherent loads; B resident)
    const USH* ah = hbuf + (size_t)(step & 1) * 32768 + (size_t)(bb * 16 + l15) * 512 + klo;
#pragma unroll
    for (int kc = 0; kc < 16; kc += 2) {
      acc0 = __builtin_amdgcn_mfma_f32_16x16x32_bf16(ld_h16(ah + kc * 32), hf[kc], acc0, 0, 0, 0);
      acc1 = __builtin_amdgcn_mfma_f32_16x16x32_bf16(ld_h16(ah + (kc + 1) * 32), hf[kc + 1], acc1, 0, 0, 0);
    }

    // gate exchange: wave g publishes its 16x16 tile (C-layout row=lhi*4+r, col=l15)
#pragma unroll
    for (int r = 0; r < 4; ++r) gex[wid][lhi * 4 + r][l15] = acc0[r] + acc1[r];
    __syncthreads();

    // elementwise LSTM: one cell per thread; pack bf16 pairs across (jl, jl^1)
    const bool dec = (step >= 50);
    {
      float gi = gex[0][bl][jl], gf = gex[1][bl][jl], gg = gex[2][bl][jl], go = gex[3][bl][jl];
      float cn = sigm(gf) * cst + sigm(gi) * tanh_(gg);
      cst = cn;
      float hn = sigm(go) * tanh_(cn);
      USH hb = f2bf(hn);
      int nb = __shfl_xor((int)hb, 1);                // neighbor (jl^1) bf16
      const int brow = bb * 16 + bl;
      if ((jl & 1) == 0) {                            // even lane stores the pair
        unsigned packed = (unsigned)hb | ((unsigned)nb << 16);
        // h store: agent-scope word write-through (native global_store_dword)
        unsigned* hp = (unsigned*)(hbuf + (size_t)((step + 1) & 1) * 32768
                                   + (size_t)brow * 512 + j0 + jl);
        __hip_atomic_store(hp, packed, __ATOMIC_RELAXED, __HIP_MEMORY_SCOPE_AGENT);
        if (dec)                                      // plain: read after kernel end
          *(unsigned*)(Hdec + ((size_t)(step - 50) * 64 + brow) * 512 + j0 + jl) = packed;
      }
    }

    if (step == 49) {   // enc->dec: swap register-resident weights (before xpart(50))
#pragma unroll
      for (int kc = 0; kc < 16; ++kc) {
        wf[kc] = *(const bf16x8*)(WihDbf + wrow + kc * 32 + klo);
        hf[kc] = *(const bf16x8*)(WhhDbf + wrow + kc * 32 + klo);
      }
    }

    if (step < 98) {
      // -------- arrive (group-local, fence-free) --------
      __syncthreads();              // waves drain vmcnt before s_barrier -> all
                                    // agent h-stores at coherence point; gex reads done
      if (tid == 0)
        __hip_atomic_store(&gflags[jb], step + 1, __ATOMIC_RELAXED, __HIP_MEMORY_SCOPE_AGENT);
      // -------- overlap: next step's x-part (Aemb + register W only) --------
      xpart(step + 1);
      // -------- wait: poll own group's 32 packed flags, one per lane --------
      if (wid == 0 && lane < 32) {
        int v;
        do { v = __hip_atomic_load(&gflags[lane], __ATOMIC_RELAXED, __HIP_MEMORY_SCOPE_AGENT); } while (v <= step);
      }
      __builtin_amdgcn_sched_barrier(0);   // compiler: nothing moves above the poll
      __syncthreads();
    }
  }
}

// ---------------------------------------------------------------- projection (m97-style 128x128, XCD-swizzled)
__global__ __launch_bounds__(256) void proj_kernel(const USH* __restrict__ Hdec,
                                                   const USH* __restrict__ WoutBf,
                                                   const float* __restrict__ bout,
                                                   float* __restrict__ S) {
  __shared__ USH Alds[128 * 64];
  __shared__ USH Blds[128 * 64];
  __shared__ float rowsum[128];
  // bijective XCD swizzle (m204): nwg=6250 = 8*781+2 -> residues 0,1 get 782 blocks
  const int xcd = blockIdx.x & 7, idx = blockIdx.x >> 3;
  const int wg = (xcd < 2 ? xcd * 782 : 2 * 782 + (xcd - 2) * 781) + idx;
  const int mt = wg % 25, nt = wg / 25;   // 25 consecutive wg share one W_out slab
  const int m0 = mt * 128, n0 = nt * 128;
  const int tid = threadIdx.x;
  const int wid = tid >> 6, lane = tid & 63;
  const int l15 = lane & 15, lhi = lane >> 4;
  const int wr = wid >> 1, wc = wid & 1;
  if (tid < 128) rowsum[tid] = 0.f;

  f32x4 acc[4][4];
  {
    f32x4 z = {0.f, 0.f, 0.f, 0.f};
#pragma unroll
    for (int mi = 0; mi < 4; ++mi)
#pragma unroll
      for (int ni = 0; ni < 4; ++ni) acc[mi][ni] = z;
  }
  const int lrow8 = lane >> 3, lcolb = (lane & 7) * 16;

  for (int kt = 0; kt < 8; ++kt) {
#pragma unroll
    for (int i = 0; i < 4; ++i) {
      int q = wid * 4 + i;                 // 0..15, each covers 8 tile rows
      int row = q * 8 + lrow8;
      const char* ga = (const char*)Hdec   + ((size_t)(m0 + row) * 512 + kt * 64) * 2 + lcolb;
      const char* gb = (const char*)WoutBf + ((size_t)(n0 + row) * 512 + kt * 64) * 2 + lcolb;
      __builtin_amdgcn_global_load_lds((const __attribute__((address_space(1))) void*)ga,
                                       (__attribute__((address_space(3))) void*)&Alds[q * 512], 16, 0, 0);
      __builtin_amdgcn_global_load_lds((const __attribute__((address_space(1))) void*)gb,
                                       (__attribute__((address_space(3))) void*)&Blds[q * 512], 16, 0, 0);
    }
    __syncthreads();
#pragma unroll
    for (int kk = 0; kk < 2; ++kk) {
      bf16x8 a[4], b[4];
#pragma unroll
      for (int mi = 0; mi < 4; ++mi)
        a[mi] = *(const bf16x8*)&Alds[(wr * 64 + mi * 16 + l15) * 64 + kk * 32 + lhi * 8];
#pragma unroll
      for (int ni = 0; ni < 4; ++ni)
        b[ni] = *(const bf16x8*)&Blds[(wc * 64 + ni * 16 + l15) * 64 + kk * 32 + lhi * 8];
#pragma unroll
      for (int mi = 0; mi < 4; ++mi)
#pragma unroll
        for (int ni = 0; ni < 4; ++ni)
          acc[mi][ni] = __builtin_amdgcn_mfma_f32_16x16x32_bf16(a[mi], b[ni], acc[mi][ni], 0, 0, 0);
    }
    __syncthreads();
  }
  // epilogue: bias + exp + per-row sum -> S (logits never hit memory)
  float bias[4];
#pragma unroll
  for (int ni = 0; ni < 4; ++ni) bias[ni] = bout[n0 + wc * 64 + ni * 16 + l15];
#pragma unroll
  for (int mi = 0; mi < 4; ++mi) {
#pragma unroll
    for (int r = 0; r < 4; ++r) {
      float s = 0.f;
#pragma unroll
      for (int ni = 0; ni < 4; ++ni) s += __expf(acc[mi][ni][r] + bias[ni]);
      s += __shfl_xor(s, 1);
      s += __shfl_xor(s, 2);
      s += __shfl_xor(s, 4);
      s += __shfl_xor(s, 8);
      if (l15 == 0) atomicAdd(&rowsum[wr * 64 + mi * 16 + lhi * 4 + r], s);
    }
  }
  __syncthreads();
  if (tid < 128) atomicAdd(&S[m0 + tid], rowsum[tid]);
}

// ---------------------------------------------------------------- target logits
__global__ void tgt_kernel(const USH* __restrict__ Hdec, const USH* __restrict__ WoutBf,
                           const float* __restrict__ bout, const int* __restrict__ tg_lines,
                           float* __restrict__ loss_tl) {
  __shared__ float part[4];
  const int tid = threadIdx.x;
  const int wid = tid >> 6, lane = tid & 63;
  const int g = blockIdx.x * 4 + wid;        // 0..3135
  const int t = g >> 6, b = g & 63;
  const int v = tg_lines[(t + 1) * 64 + b];  // tgt_next
  bf16x8 hv = *(const bf16x8*)(Hdec + (size_t)g * 512 + lane * 8);
  bf16x8 wv = *(const bf16x8*)(WoutBf + (size_t)v * 512 + lane * 8);
  float s = 0.f;
#pragma unroll
  for (int j = 0; j < 8; ++j) s += bf2f((USH)hv[j]) * bf2f((USH)wv[j]);
#pragma unroll
  for (int m = 1; m < 64; m <<= 1) s += __shfl_xor(s, m);
  if (lane == 0) part[wid] = s + bout[v];
  __syncthreads();
  if (tid == 0) atomicAdd(loss_tl, part[0] + part[1] + part[2] + part[3]);
}

// ---------------------------------------------------------------- finalize
__global__ void fin_kernel(const float* __restrict__ S, const float* __restrict__ loss_tl,
                           float* __restrict__ out) {
  __shared__ float part[4];
  const int tid = threadIdx.x;
  float s = 0.f;
  for (int m = tid; m < 3136; m += 256) s += logf(S[m]);
#pragma unroll
  for (int m = 1; m < 64; m <<= 1) s += __shfl_xor(s, m);
  if ((tid & 63) == 0) part[tid >> 6] = s;
  __syncthreads();
  if (tid == 0) out[0] = (part[0] + part[1] + part[2] + part[3] - loss_tl[0]) * (1.f / 64.f);
}

// ---------------------------------------------------------------- launch
extern "C" void kernel_launch(void* const* d_in, const int* in_sizes, int n_in,
                              void* d_out, int out_size, void* d_ws, size_t ws_size,
                              hipStream_t stream) {
  (void)in_sizes; (void)n_in; (void)out_size; (void)ws_size;
  const int* in_lines  = (const int*)d_in[0];
  const int* tg_lines  = (const int*)d_in[1];
  const float* emb_in  = (const float*)d_in[2];
  const float* emb_tgt = (const float*)d_in[3];
  const float* WihE = (const float*)d_in[4];
  const float* WhhE = (const float*)d_in[5];
  const float* bihE = (const float*)d_in[6];
  const float* bhhE = (const float*)d_in[7];
  const float* WihD = (const float*)d_in[8];
  const float* WhhD = (const float*)d_in[9];
  const float* bihD = (const float*)d_in[10];
  const float* bhhD = (const float*)d_in[11];
  const float* Wout = (const float*)d_in[12];
  const float* bout = (const float*)d_in[13];

  char* ws = (char*)d_ws;
  USH* WoutBf  = (USH*)(ws + 0u);          // 32,768,000
  USH* WihEbf  = (USH*)(ws + 32768000u);   // +2,097,152 each
  USH* WhhEbf  = (USH*)(ws + 34865152u);
  USH* WihDbf  = (USH*)(ws + 36962304u);
  USH* WhhDbf  = (USH*)(ws + 39059456u);
  USH* Aemb    = (USH*)(ws + 41156608u);   // 6336*512*2 = 6,488,064
  USH* hbuf    = (USH*)(ws + 47644672u);   // 2 * 64*512*2 = 131,072
  USH* Hdec    = (USH*)(ws + 47775744u);   // 3200*512*2 = 3,276,800
  float* S     = (float*)(ws + 51052544u); // 3200*4
  float* bsumE = (float*)(ws + 51065344u);
  float* bsumD = (float*)(ws + 51073536u);
  float* loss_tl = (float*)(ws + 51081728u);
  int* flags   = (int*)(ws + 51085312u);   // 4 groups x 64 ints (packed per group)

  prep_kernel<<<1024, 256, 0, stream>>>(in_lines, tg_lines, emb_in, emb_tgt,
      WihE, WhhE, bihE, bhhE, WihD, WhhD, bihD, bhhD,
      WihEbf, WhhEbf, WihDbf, WhhDbf, Aemb, hbuf, Hdec, bsumE, bsumD, S, loss_tl, flags);

  // plain launch (capture-safe); 256 blocks <= 256 CUs -> co-resident by capacity.
  recur_kernel<<<256, 256, 0, stream>>>(Aemb, WihEbf, WhhEbf, WihDbf, WhhDbf,
                                        bsumE, bsumD, hbuf, Hdec, flags, Wout, WoutBf);

  proj_kernel<<<6250, 256, 0, stream>>>(Hdec, WoutBf, bout, S);
  tgt_kernel<<<784, 256, 0, stream>>>(Hdec, WoutBf, bout, tg_lines, loss_tl);
  fin_kernel<<<1, 256, 0, stream>>>(S, loss_tl, (float*)d_out);
}